// Round 4
// baseline (21.072 us; speedup 1.0000x reference)
//
#include <hip/hip_runtime.h>
#include <hip/hip_bf16.h>

using bf16x8 = __attribute__((ext_vector_type(8))) short;
using f32x4  = __attribute__((ext_vector_type(4))) float;

static constexpr int kN          = 100000;
static constexpr int kFIN        = 128;
static constexpr int kTermStride = 192 * 64;     // W term stride in floats
static constexpr int kTiles      = kN / 16;      // 6250, exact
static constexpr int kBlocks     = 1024;         // 4 per CU exactly
static constexpr int kWaves      = kBlocks * 4;  // 4096

// round-to-nearest-even f32 -> bf16 (inputs are finite; no NaN handling)
__device__ __forceinline__ short f2bf(float v) {
    union { float f; unsigned u; } a; a.f = v;
    unsigned r = a.u + 0x7fffu + ((a.u >> 16) & 1u);
    return (short)(r >> 16);
}

// Fast activations: v_exp_f32 / v_rcp_f32 (~1e-7 rel err, << bf16 noise).
__device__ __forceinline__ float rcp_fast(float x) { return __builtin_amdgcn_rcpf(x); }
__device__ __forceinline__ float sigmoid_fast(float x) {
    return rcp_fast(1.0f + __expf(-x));
}
__device__ __forceinline__ float tanh_fast(float x) {
    float e = __expf(2.0f * x);          // overflow->inf->rcp->0 => tanh=1
    return 1.0f - 2.0f * rcp_fast(e + 1.0f);
}

// One fused kernel. Each block packs W_sum = W[0,0,:128,:]+W[1,0,:128,:]
// (z and h mats) bf16 into LDS in MFMA B-fragment order, then each wave
// computes 1-2 16-node tiles: x -> bf16 -> two [16x128]x[128x64] MFMAs ->
// GRU epilogue -> dot with Wlin -> out[16].
//
// Pack layout, element (mat,k,c):  kk=k>>5, g=(k>>3)&3, e=k&7
//   short idx = mat*8192 + kk*2048 + (c>>4)*512 + g*128 + (c&15)*8 + e
// With fidx = it*1024 + t*4 + i (t=thread, it=0..7, i=0..3):
//   idx = [jt*512 + (s>>3)*128 + cl*8 + (s&7)]   (runtime, per-thread)
//       + mat*8192 + (it>>1)*2048 + (it&1)*256   (compile-time)
//       + i*8                                    (compile-time)
// where s=t>>4, cl=(t*4)&15, jt=((t*4)&63)>>4.
__global__ __launch_bounds__(256, 4) void fused_gcn(
    const float* __restrict__ x,
    const float* __restrict__ Wz,
    const float* __restrict__ bz,
    const float* __restrict__ Wh,
    const float* __restrict__ bh,
    const float* __restrict__ wlin,
    const float* __restrict__ blin,
    float* __restrict__ out)
{
    __shared__ short lw[16384];   // 32 KB packed weights

    const int t    = threadIdx.x;
    const int wid  = t >> 6;
    const int lane = t & 63;
    const int r    = lane & 15;   // A row within tile / C channel low bits
    const int g    = lane >> 4;   // k-group
    const int gw   = blockIdx.x * 4 + wid;
    const int t0   = gw;                              // always valid (< 4096)
    const int t1   = (gw + kWaves < kTiles) ? gw + kWaves : -1;

    f32x4 f[8];
    auto load_x = [&](int tile) {
        const float* xrow = x + (size_t)(tile * 16 + r) * kFIN;
        #pragma unroll
        for (int kk = 0; kk < 4; ++kk) {
            f[kk * 2]     = *(const f32x4*)(xrow + kk * 32 + g * 8);
            f[kk * 2 + 1] = *(const f32x4*)(xrow + kk * 32 + g * 8 + 4);
        }
    };

    load_x(t0);   // first tile's HBM loads in flight during the weight pack

    // Hoisted per-lane epilogue constants (issued early, used after MFMA)
    float bzc[4], bhc[4], wlc[4];
    #pragma unroll
    for (int jt = 0; jt < 4; ++jt) {
        int c = jt * 16 + r;
        bzc[jt] = bz[c]; bhc[jt] = bh[c]; wlc[jt] = wlin[c];
    }
    const float bl = blin[0];

    // ---- pack weights into LDS (strength-reduced addressing) ----
    {
        const int s  = t >> 4;
        const int c0 = (t << 2) & 63;
        char* dstb = (char*)lw +
            ((c0 >> 4) * 512 + (s >> 3) * 128 + (c0 & 15) * 8 + (s & 7)) * 2;
        #pragma unroll
        for (int mat = 0; mat < 2; ++mat) {
            const float* W = mat ? Wh : Wz;
            #pragma unroll
            for (int it = 0; it < 8; ++it) {
                const int fidx = it * 1024 + t * 4;
                f32x4 w0 = *(const f32x4*)(W + fidx);
                f32x4 w1 = *(const f32x4*)(W + kTermStride + fidx);
                const int off = (mat * 8192 + (it >> 1) * 2048 + (it & 1) * 256) * 2;
                #pragma unroll
                for (int i = 0; i < 4; ++i)
                    *(short*)(dstb + off + i * 16) = f2bf(w0[i] + w1[i]);
            }
        }
    }
    __syncthreads();

    bf16x8 a[4];
    auto cvt = [&]() {
        #pragma unroll
        for (int kk = 0; kk < 4; ++kk) {
            #pragma unroll
            for (int e = 0; e < 4; ++e) {
                a[kk][e]     = f2bf(f[kk * 2][e]);
                a[kk][e + 4] = f2bf(f[kk * 2 + 1][e]);
            }
        }
    };

    auto compute_tile = [&](int tile) {
        f32x4 accz[4], acch[4];
        #pragma unroll
        for (int jt = 0; jt < 4; ++jt) {
            accz[jt] = f32x4{0.f, 0.f, 0.f, 0.f};
            acch[jt] = f32x4{0.f, 0.f, 0.f, 0.f};
        }
        #pragma unroll
        for (int kk = 0; kk < 4; ++kk) {
            #pragma unroll
            for (int jt = 0; jt < 4; ++jt) {
                bf16x8 wz = *(const bf16x8*)&lw[(kk * 4 + jt) * 512 + lane * 8];
                bf16x8 wh = *(const bf16x8*)&lw[8192 + (kk * 4 + jt) * 512 + lane * 8];
                accz[jt] = __builtin_amdgcn_mfma_f32_16x16x32_bf16(a[kk], wz, accz[jt], 0, 0, 0);
                acch[jt] = __builtin_amdgcn_mfma_f32_16x16x32_bf16(a[kk], wh, acch[jt], 0, 0, 0);
            }
        }
        // epilogue: C layout channel = jt*16 + r, node-in-tile = g*4 + reg
        float contrib[4] = {0.f, 0.f, 0.f, 0.f};
        #pragma unroll
        for (int jt = 0; jt < 4; ++jt) {
            #pragma unroll
            for (int i = 0; i < 4; ++i) {
                float z  = sigmoid_fast(accz[jt][i] + bzc[jt]);
                float ht = tanh_fast(acch[jt][i] + bhc[jt]);
                float H  = (1.0f - z) * ht;
                contrib[i] += fmaxf(H, 0.f) * wlc[jt];
            }
        }
        #pragma unroll
        for (int m = 1; m < 16; m <<= 1) {
            #pragma unroll
            for (int i = 0; i < 4; ++i)
                contrib[i] += __shfl_xor(contrib[i], m, 64);
        }
        if (r == 0) {
            f32x4 o;
            #pragma unroll
            for (int i = 0; i < 4; ++i) o[i] = contrib[i] + bl;
            *(f32x4*)(out + tile * 16 + g * 4) = o;
        }
    };

    // tile 0 (prefetch tile 1 during its compute)
    cvt();
    if (t1 >= 0) load_x(t1);
    compute_tile(t0);
    // tile 1 (first 2154 waves only)
    if (t1 >= 0) {
        cvt();
        compute_tile(t1);
    }
}

extern "C" void kernel_launch(void* const* d_in, const int* in_sizes, int n_in,
                              void* d_out, int out_size, void* d_ws, size_t ws_size,
                              hipStream_t stream) {
    const float* x    = (const float*)d_in[0];
    // d_in[1] edge_index, d_in[2] edge_weight: dead code in reference (K=1, H0=0)
    const float* Wz   = (const float*)d_in[3];
    const float* bz   = (const float*)d_in[4];
    // d_in[5] Wr, d_in[6] br: dead (R*H0 == 0)
    const float* Wh   = (const float*)d_in[7];
    const float* bh   = (const float*)d_in[8];
    const float* wlin = (const float*)d_in[9];
    const float* blin = (const float*)d_in[10];

    fused_gcn<<<dim3(kBlocks), dim3(256), 0, stream>>>(
        x, Wz, bz, Wh, bh, wlin, blin, (float*)d_out);
}